// Round 9
// baseline (205.527 us; speedup 1.0000x reference)
//
#include <hip/hip_runtime.h>
#include <stdint.h>

// Problem constants
#define T_TOK 16384     // 32*512 tokens
#define NE 8            // experts
#define EPSV 1e-8f
#define MAXC64  264     // max 64-token chunks
#define MAXC16  1032    // max 16-token chunks

// ws layout (byte offsets). Total ~25.7 MiB (xs ELIMINATED in R18 — gemm gathers from nodes).
#define WS_PERM   0                         // int[16384]
#define WS_PART   65536                     // int[64][8] per-block expert counts
#define WS_OFFS   67584                     // int[9]
#define WS_WT     131072                    // bf16[8][512][1024]  (W1|R1 transposed, B^T layout)
#define WS_H1     (WS_WT + 8*512*1024*2)    // bf16[16448][512] (64 slack rows)
#define WS_W2T    (WS_H1 + 16448*512*2)     // bf16[8][64][256]
#define WS_W3T    (WS_W2T + 8*64*256*2)     // bf16[8][32][64]
#define WS_W4T    (WS_W3T + 8*32*64*2)      // bf16[8][16][32]  (n>=14 zero)
#define WS_R2T    (WS_W4T + 8*16*32*2)      // bf16[8][16][256] (n>=3 zero)

typedef __attribute__((ext_vector_type(8))) short bf16x8;
typedef __attribute__((ext_vector_type(4))) float f32x4;

__device__ __forceinline__ unsigned short f2bf(float f) {
    unsigned u = __float_as_uint(f);
    u += 0x7fffu + ((u >> 16) & 1u);   // RNE
    return (unsigned short)(u >> 16);
}

// fp32x8 -> bf16x8 convert + 16B LDS write (ds_write_b128)
__device__ __forceinline__ void cvt_wr16(short* dst, float4 a, float4 b) {
    unsigned u0 = (unsigned)f2bf(a.x) | ((unsigned)f2bf(a.y) << 16);
    unsigned u1 = (unsigned)f2bf(a.z) | ((unsigned)f2bf(a.w) << 16);
    unsigned u2 = (unsigned)f2bf(b.x) | ((unsigned)f2bf(b.y) << 16);
    unsigned u3 = (unsigned)f2bf(b.z) | ((unsigned)f2bf(b.w) << 16);
    *(uint4*)dst = make_uint4(u0, u1, u2, u3);
}

// async global->LDS, 16B per lane. LDS DEST = wave-uniform base + lane*16.
__device__ __forceinline__ void gl_lds16(const void* g, void* l) {
    __builtin_amdgcn_global_load_lds(
        (const __attribute__((address_space(1))) void*)g,
        (__attribute__((address_space(3))) void*)l,
        16, 0, 0);
}

// chunk id -> (expert, base, len) from the 9-entry prefix array. Uniform scalar loop.
__device__ __forceinline__ bool chunk_lookup(const int* __restrict__ offs, int c, int csize,
                                             int& e, int& base, int& len) {
    int acc = 0;
#pragma unroll
    for (int i = 0; i < NE; i++) {
        int s = offs[i], t = offs[i + 1];
        int cc = (t - s + csize - 1) / csize;
        if (c < acc + cc) {
            e = i;
            base = s + (c - acc) * csize;
            len = (t - base < csize) ? (t - base) : csize;
            return true;
        }
        acc += cc;
    }
    return false;
}

// ---------------- kernel 1: fused [wcvt | hist] ----------------
// blocks 0..1023:    W1|R1 transpose-convert (+ tail-weight convert on ny==0)
// blocks 1024..1087: per-block expert histogram of sem
__global__ __launch_bounds__(256) void k_prep1(const float* __restrict__ W1,
                                               const float* __restrict__ R1,
                                               const float* __restrict__ W2,
                                               const float* __restrict__ W3,
                                               const float* __restrict__ W4,
                                               const float* __restrict__ R2,
                                               const int* __restrict__ sem,
                                               unsigned short* __restrict__ wt,
                                               unsigned short* __restrict__ w2t,
                                               unsigned short* __restrict__ w3t,
                                               unsigned short* __restrict__ w4t,
                                               unsigned short* __restrict__ r2t,
                                               int* __restrict__ ws_i) {
    __shared__ float tile[64][65];
    int id = blockIdx.x, tid = threadIdx.x;
    if (id >= 1024) {
        __shared__ int cnt[NE];
        int hb = id - 1024, lane = tid & 63;
        if (tid < NE) cnt[tid] = 0;
        __syncthreads();
        int s = sem[hb * 256 + tid];
#pragma unroll
        for (int e = 0; e < NE; e++) {
            unsigned long long m = __ballot(s == e);
            if (lane == e) atomicAdd(&cnt[e], (int)__popcll(m));
        }
        __syncthreads();
        if (tid < NE) ws_i[(WS_PART >> 2) + hb * NE + tid] = cnt[tid];
        return;
    }
    int e = id >> 7, rem = id & 127;
    int ny = rem >> 4, kx = rem & 15;
    int k0 = kx * 64, n0 = ny * 64;
    const float* src = (n0 < 256) ? (W1 + (size_t)e * 1024 * 256 + n0)
                                  : (R1 + (size_t)e * 1024 * 256 + (n0 - 256));
    int rr = tid >> 4;
    int cg = (tid & 15) * 4;
#pragma unroll
    for (int p = 0; p < 4; p++) {
        int kk = p * 16 + rr;
        float4 v = *(const float4*)(src + (size_t)(k0 + kk) * 256 + cg);
        tile[kk][cg] = v.x; tile[kk][cg + 1] = v.y; tile[kk][cg + 2] = v.z; tile[kk][cg + 3] = v.w;
    }
    __syncthreads();
    int nn = tid >> 3;
    int k8 = tid & 7;
#pragma unroll
    for (int p = 0; p < 2; p++) {
        int n = p * 32 + nn;
        unsigned w[4];
#pragma unroll
        for (int j = 0; j < 4; j++) {
            float f0 = tile[k8 * 8 + 2 * j][n];
            float f1 = tile[k8 * 8 + 2 * j + 1][n];
            w[j] = (unsigned)f2bf(f0) | ((unsigned)f2bf(f1) << 16);
        }
        *(uint4*)(wt + (size_t)(e * 512 + n0 + n) * 1024 + k0 + k8 * 8) =
            make_uint4(w[0], w[1], w[2], w[3]);
    }
    if (ny == 0) {
        int x = kx;
        for (int j = tid; j < 1024; j += 256) {
            int idx = x * 1024 + j; int k = idx & 255, n = idx >> 8;
            w2t[(size_t)(e * 64 + n) * 256 + k] = f2bf(W2[(size_t)e * 16384 + k * 64 + n]);
        }
        if (tid < 128) {
            int idx = x * 128 + tid; int k = idx & 63, n = idx >> 6;
            w3t[(size_t)(e * 32 + n) * 64 + k] = f2bf(W3[(size_t)e * 2048 + k * 32 + n]);
        }
        if (tid < 32) {
            int idx = x * 32 + tid; int k = idx & 31, n = idx >> 5;
            w4t[(size_t)(e * 16 + n) * 32 + k] = (n < 14) ? f2bf(W4[(size_t)e * 448 + k * 14 + n])
                                                          : (unsigned short)0;
        }
        {
            int idx = x * 256 + tid; int k = idx & 255, n = idx >> 8;
            r2t[(size_t)(e * 16 + n) * 256 + k] = (n < 3) ? f2bf(R2[(size_t)e * 768 + k * 3 + n])
                                                          : (unsigned short)0;
        }
    }
}

// ---------------- kernel 2: perm-only (R18: the 100MB xs copy is DELETED) ----------------
// 64 blocks, one per 256-token group. Same deterministic dest computation as the old
// k_scatter (ballot + per-wave prefix), writes perm[dest]=token and (block 0) offs.
__global__ __launch_bounds__(256) void k_perm(const int* __restrict__ sem,
                                              int* __restrict__ ws_i) {
    __shared__ int parts[512];
    __shared__ int tot[NE], preb[NE], ebase[NE + 1];
    __shared__ int wcnt[4][NE];
    int g = blockIdx.x;
    int tid = threadIdx.x, wave = tid >> 6, lane = tid & 63;
    parts[tid] = ws_i[(WS_PART >> 2) + tid];
    parts[256 + tid] = ws_i[(WS_PART >> 2) + 256 + tid];
    __syncthreads();
    if (tid < NE) {
        int t = 0, p = 0;
        for (int bb = 0; bb < 64; bb++) {
            int v = parts[bb * NE + tid];
            t += v;
            if (bb < g) p += v;
        }
        tot[tid] = t; preb[tid] = p;
    }
    __syncthreads();
    if (tid == 0) {
        int base = 0;
        for (int e = 0; e < NE; e++) { ebase[e] = base; base += tot[e]; }
        ebase[NE] = base;
        if (g == 0)
            for (int e = 0; e <= NE; e++) ws_i[(WS_OFFS >> 2) + e] = ebase[e];
    }
    int i = g * 256 + tid;
    int s = sem[i];
    int rank = 0;
#pragma unroll
    for (int e = 0; e < NE; e++) {
        unsigned long long m = __ballot(s == e);
        if (s == e) rank = (int)__popcll(m & ((1ull << lane) - 1ull));
        if (lane == e) wcnt[wave][e] = (int)__popcll(m);
    }
    __syncthreads();   // orders ebase (tid0) AND wcnt writes before reads below
    int wpre = 0;
#pragma unroll
    for (int w = 0; w < 4; w++)
        if (w < wave) wpre += wcnt[w][s];
    int dest = ebase[s] + preb[s] + wpre + rank;
    ws_i[(WS_PERM >> 2) + dest] = i;
}

// ---------------- kernel 3: layer-1 GEMM — gather-A from nodes (no xs) ----------------
// Verified R12 core (depth-2 counted pipeline, same LDS swizzle + MFMA reads) with A-staging
// changed from gl_lds(xs-sorted-bf16) to: gather fp32 rows from nodes via perm, convert
// (same f2bf => bit-identical), ds_write_b128 to the SAME linear slot the gl_lds used
// (conflict-free by construction). T14 split: issue loads before compute, write after.
// B path unchanged. XCD swizzle (bijective 1056=8x132) keeps A/B panels L2-resident.
__global__ __launch_bounds__(256) void k_gemm(const float* __restrict__ nodes,
                                              const unsigned short* __restrict__ wt,
                                              const float* __restrict__ b1,
                                              const float* __restrict__ rb1,
                                              const int* __restrict__ ws_i,
                                              unsigned short* __restrict__ h1) {
    __shared__ __align__(16) short As[2][64 * 64];    // 16 KB
    __shared__ __align__(16) short Bs[2][128 * 64];   // 32 KB
    int bid = blockIdx.x;
    int wgid = (bid & 7) * ((MAXC64 * 4) / 8) + (bid >> 3);   // bijective: 1056 = 8*132
    int c = wgid >> 2, nblk = wgid & 3;
    int e, base, len;
    if (!chunk_lookup(ws_i + (WS_OFFS >> 2), c, 64, e, base, len)) return;
    int n0 = nblk * 128;
    int tid = threadIdx.x;
    int wave = tid >> 6, lane = tid & 63;
    int quad = lane >> 4, lr = lane & 15;
    int wn = wave * 32;   // each wave: all 64 rows x 32 cols

    f32x4 acc[4][2];
#pragma unroll
    for (int i = 0; i < 4; i++)
#pragma unroll
        for (int j = 0; j < 2; j++) acc[i][j] = (f32x4){0.f, 0.f, 0.f, 0.f};

    const int* perm = ws_i + (WS_PERM >> 2);
    const unsigned short* Bg = wt + (size_t)(e * 512 + n0) * 1024;

    // A staging geometry: pass i in {0,1}: slot s=i*256+tid; row r=s>>3; swz chunk cs=(s&7)^(r&7).
    // LDS write is LINEAR at slot s*16B (zero bank conflict); source is the pre-swizzled
    // global segment — exactly the verified gl_lds pattern, with fp32 gather + convert.
    const float* apA[2];
    int dstA[2];
#pragma unroll
    for (int i = 0; i < 2; i++) {
        int s = i * 256 + tid;
        int r = s >> 3, cs = (s & 7) ^ (r & 7);
        int gidx = base + r;
        if (gidx > T_TOK - 1) gidx = T_TOK - 1;   // last-chunk slack: clamp (masked at epilogue)
        int tok = perm[gidx];
        apA[i] = nodes + (size_t)tok * 1024 + cs * 8;
        dstA[i] = s * 8;
    }
    const unsigned short* srcB[4];
    int dstB[4];
#pragma unroll
    for (int i = 0; i < 4; i++) {
        int s = i * 256 + wave * 64 + lane;
        int r = s >> 3, cs = (s & 7) ^ (r & 7);
        srcB[i] = Bg + (size_t)r * 1024 + cs * 8;
        dstB[i] = (i * 256 + wave * 64) * 8;
    }

    float4 fa0, fb0, fa1, fb1;   // in-flight A fragments (named: rule #20)

    // prologue: stage step 0
    fa0 = *(const float4*)(apA[0]); fb0 = *(const float4*)(apA[0] + 4);
    fa1 = *(const float4*)(apA[1]); fb1 = *(const float4*)(apA[1] + 4);
#pragma unroll
    for (int i = 0; i < 4; i++) gl_lds16(srcB[i], &Bs[0][dstB[i]]);
    cvt_wr16(&As[0][dstA[0]], fa0, fb0);    // compiler waits the A loads here
    cvt_wr16(&As[0][dstA[1]], fa1, fb1);
    asm volatile("s_waitcnt vmcnt(0) lgkmcnt(0)" ::: "memory");
    __builtin_amdgcn_sched_barrier(0);
    __builtin_amdgcn_s_barrier();

    for (int kb = 0; kb < 16; kb++) {
        int cur = kb & 1;
        int nxt = cur ^ 1;
        if (kb < 15) {
            // issue step kb+1: A fp32 loads (to regs) + B DMA. All stay in flight across compute.
            fa0 = *(const float4*)(apA[0] + (kb + 1) * 64);
            fb0 = *(const float4*)(apA[0] + (kb + 1) * 64 + 4);
            fa1 = *(const float4*)(apA[1] + (kb + 1) * 64);
            fb1 = *(const float4*)(apA[1] + (kb + 1) * 64 + 4);
#pragma unroll
            for (int i = 0; i < 4; i++) gl_lds16(srcB[i] + (kb + 1) * 64, &Bs[nxt][dstB[i]]);
        }
        __builtin_amdgcn_sched_barrier(0);   // pin issues above compute

        const short* Ab = As[cur];
        const short* Bb = Bs[cur];
        bf16x8 af[2][4], bfr[2][2];
#pragma unroll
        for (int im = 0; im < 4; im++) {
            int r = im * 16 + lr;
#pragma unroll
            for (int kh = 0; kh < 2; kh++) {
                int q = kh * 4 + quad;
                af[kh][im] = *(const bf16x8*)(Ab + (r * 8 + (q ^ (r & 7))) * 8);
            }
        }
#pragma unroll
        for (int in = 0; in < 2; in++) {
            int r = wn + in * 16 + lr;
#pragma unroll
            for (int kh = 0; kh < 2; kh++) {
                int q = kh * 4 + quad;
                bfr[kh][in] = *(const bf16x8*)(Bb + (r * 8 + (q ^ (r & 7))) * 8);
            }
        }
#pragma unroll
        for (int kh = 0; kh < 2; kh++)
#pragma unroll
            for (int im = 0; im < 4; im++)
#pragma unroll
                for (int in = 0; in < 2; in++)
                    acc[im][in] = __builtin_amdgcn_mfma_f32_16x16x32_bf16(af[kh][im], bfr[kh][in], acc[im][in], 0, 0, 0);

        if (kb < 15) {
            // convert+write A(kb+1) (compiler inserts the vmcnt wait for fa*/fb* here),
            // then drain ds_writes + B DMA and release both buffers.
            cvt_wr16(&As[nxt][dstA[0]], fa0, fb0);
            cvt_wr16(&As[nxt][dstA[1]], fa1, fb1);
            asm volatile("s_waitcnt vmcnt(0) lgkmcnt(0)" ::: "memory");
            __builtin_amdgcn_sched_barrier(0);
            __builtin_amdgcn_s_barrier();
        }
    }

    // epilogue: + bias, relu, store bf16. C/D layout: col=lane&15, row=quad*4+reg.
#pragma unroll
    for (int in = 0; in < 2; in++) {
        int gcol = n0 + wn + in * 16 + lr;
        float bias = (gcol < 256) ? b1[e * 256 + gcol] : rb1[e * 256 + gcol - 256];
#pragma unroll
        for (int im = 0; im < 4; im++) {
#pragma unroll
            for (int v = 0; v < 4; v++) {
                int r = im * 16 + quad * 4 + v;
                if (r < len) {
                    float val = fmaxf(acc[im][in][v] + bias, 0.f);
                    h1[(size_t)(base + r) * 512 + gcol] = f2bf(val);
                }
            }
        }
    }
}

// ---------------- kernel 4: MFMA tail — 16-token blocks, 4x wave parallelism ----------------
__global__ __launch_bounds__(256) void k_tail(const unsigned short* __restrict__ h1,
                                              const int* __restrict__ ws_i,
                                              const unsigned short* __restrict__ w2t,
                                              const unsigned short* __restrict__ w3t,
                                              const unsigned short* __restrict__ w4t,
                                              const unsigned short* __restrict__ r2t,
                                              const float* __restrict__ b2,
                                              const float* __restrict__ b3,
                                              const float* __restrict__ b4,
                                              const float* __restrict__ rb2,
                                              const int* __restrict__ lengths,
                                              float* __restrict__ out) {
    __shared__ __align__(16) unsigned short h2s[16][64];
    __shared__ __align__(16) unsigned short h3s[16][32];

    int e, base, len;
    if (!chunk_lookup(ws_i + (WS_OFFS >> 2), blockIdx.x, 16, e, base, len)) return;
    int tid = threadIdx.x, wave = tid >> 6, lane = tid & 63;
    int quad = lane >> 4, lr = lane & 15;
    int lead = blockIdx.x & 3;   // rotate leader role across blocks

    const unsigned short* Ap = h1 + (size_t)base * 512;

    // layer 2: wave w computes output cols w*16..w*16+15 for all 16 tokens
    f32x4 acc2;
    { float bb = b2[e * 64 + wave * 16 + lr]; acc2 = (f32x4){bb, bb, bb, bb}; }
    f32x4 accr;
    { float bb = (lr < 3) ? rb2[e * 3 + lr] : 0.f; accr = (f32x4){bb, bb, bb, bb}; }

    const unsigned short* W2e = w2t + (size_t)e * 64 * 256;
    const unsigned short* R2e = r2t + (size_t)e * 16 * 256;
#pragma unroll
    for (int kk = 0; kk < 8; kk++) {
        int k0 = kk * 32;
        bf16x8 a = *(const bf16x8*)(Ap + lr * 512 + k0 + quad * 8);
        bf16x8 b = *(const bf16x8*)(W2e + (wave * 16 + lr) * 256 + k0 + quad * 8);
        acc2 = __builtin_amdgcn_mfma_f32_16x16x32_bf16(a, b, acc2, 0, 0, 0);
        if (wave == lead) {   // leader also accumulates the rot path (cols 256..511 of h1)
            bf16x8 ar = *(const bf16x8*)(Ap + lr * 512 + 256 + k0 + quad * 8);
            bf16x8 br = *(const bf16x8*)(R2e + lr * 256 + k0 + quad * 8);
            accr = __builtin_amdgcn_mfma_f32_16x16x32_bf16(ar, br, accr, 0, 0, 0);
        }
    }
#pragma unroll
    for (int v = 0; v < 4; v++)
        h2s[quad * 4 + v][wave * 16 + lr] = f2bf(fmaxf(acc2[v], 0.f));
    __syncthreads();
    if (wave != lead) return;

    // layer 3 (leader wave): K=64, N=32
    f32x4 acc3[2];
#pragma unroll
    for (int t = 0; t < 2; t++) {
        float bb = b3[e * 32 + t * 16 + lr];
        acc3[t] = (f32x4){bb, bb, bb, bb};
    }
    const unsigned short* W3e = w3t + (size_t)e * 32 * 64;
#pragma unroll
    for (int kk = 0; kk < 2; kk++) {
        int k0 = kk * 32;
        bf16x8 a = *(const bf16x8*)(&h2s[lr][k0 + quad * 8]);
#pragma unroll
        for (int t = 0; t < 2; t++) {
            bf16x8 b = *(const bf16x8*)(W3e + (t * 16 + lr) * 64 + k0 + quad * 8);
            acc3[t] = __builtin_amdgcn_mfma_f32_16x16x32_bf16(a, b, acc3[t], 0, 0, 0);
        }
    }
#pragma unroll
    for (int t = 0; t < 2; t++)
#pragma unroll
        for (int v = 0; v < 4; v++)
            h3s[quad * 4 + v][t * 16 + lr] = f2bf(fmaxf(acc3[t][v], 0.f));

    // layer 4: K=32, N=14 (padded 16)
    f32x4 acc4;
    { float bb = (lr < 14) ? b4[e * 14 + lr] : 0.f; acc4 = (f32x4){bb, bb, bb, bb}; }
    {
        bf16x8 a = *(const bf16x8*)(&h3s[lr][quad * 8]);
        bf16x8 b = *(const bf16x8*)(w4t + ((size_t)e * 16 + lr) * 32 + quad * 8);
        acc4 = __builtin_amdgcn_mfma_f32_16x16x32_bf16(a, b, acc4, 0, 0, 0);
    }

    const int* perm = ws_i + (WS_PERM >> 2);
#pragma unroll
    for (int v = 0; v < 4; v++) {
        int t = quad * 4 + v;
        if (t < len) {
            int token = perm[base + t];
            int bi = token >> 9, ni = token & 511;
            int valid = ni < lengths[bi];
            if (lr < 14) out[(size_t)token * 17 + lr] = valid ? acc4[v] : EPSV;
            if (lr < 3)  out[(size_t)token * 17 + 14 + lr] = valid ? accr[v] : EPSV;
        }
    }
}

extern "C" void kernel_launch(void* const* d_in, const int* in_sizes, int n_in,
                              void* d_out, int out_size, void* d_ws, size_t ws_size,
                              hipStream_t stream) {
    (void)in_sizes; (void)n_in; (void)out_size; (void)ws_size;
    const float* nodes   = (const float*)d_in[0];
    const int*   sem     = (const int*)d_in[1];
    const int*   lengths = (const int*)d_in[2];
    const float* W1 = (const float*)d_in[3];
    const float* b1 = (const float*)d_in[4];
    const float* W2 = (const float*)d_in[5];
    const float* b2 = (const float*)d_in[6];
    const float* W3 = (const float*)d_in[7];
    const float* b3 = (const float*)d_in[8];
    const float* W4 = (const float*)d_in[9];
    const float* b4 = (const float*)d_in[10];
    const float* R1  = (const float*)d_in[11];
    const float* rb1 = (const float*)d_in[12];
    const float* R2  = (const float*)d_in[13];
    const float* rb2 = (const float*)d_in[14];
    float* out = (float*)d_out;

    char* ws = (char*)d_ws;
    int* ws_i = (int*)ws;
    unsigned short* wt  = (unsigned short*)(ws + WS_WT);
    unsigned short* h1  = (unsigned short*)(ws + WS_H1);
    unsigned short* w2t = (unsigned short*)(ws + WS_W2T);
    unsigned short* w3t = (unsigned short*)(ws + WS_W3T);
    unsigned short* w4t = (unsigned short*)(ws + WS_W4T);
    unsigned short* r2t = (unsigned short*)(ws + WS_R2T);

    hipLaunchKernelGGL(k_prep1, dim3(1088), dim3(256), 0, stream,
                       W1, R1, W2, W3, W4, R2, sem, wt, w2t, w3t, w4t, r2t, ws_i);
    hipLaunchKernelGGL(k_perm, dim3(64), dim3(256), 0, stream, sem, ws_i);
    hipLaunchKernelGGL(k_gemm, dim3(MAXC64 * 4), dim3(256), 0, stream,
                       nodes, (const unsigned short*)wt, b1, rb1, (const int*)ws_i, h1);
    hipLaunchKernelGGL(k_tail, dim3(MAXC16), dim3(256), 0, stream,
                       (const unsigned short*)h1, (const int*)ws_i,
                       (const unsigned short*)w2t, (const unsigned short*)w3t,
                       (const unsigned short*)w4t, (const unsigned short*)r2t,
                       b2, b3, b4, rb2, lengths, out);
}

// Round 10
// 198.802 us; speedup vs baseline: 1.0338x; 1.0338x over previous
//
#include <hip/hip_runtime.h>
#include <stdint.h>

// Problem constants
#define T_TOK 16384     // 32*512 tokens
#define NE 8            // experts
#define EPSV 1e-8f
#define MAXC64  264     // max 64-token chunks
#define MAXC16  1032    // max 16-token chunks

// ws layout (byte offsets). Total ~25.7 MiB (xs eliminated — gemm gathers from nodes).
#define WS_PERM   0                         // int[16384]
#define WS_PART   65536                     // int[64][8] per-block expert counts
#define WS_OFFS   67584                     // int[9]
#define WS_WT     131072                    // bf16[8][512][1024]  (W1|R1 transposed, B^T layout)
#define WS_H1     (WS_WT + 8*512*1024*2)    // bf16[16448][512] (64 slack rows)
#define WS_W2T    (WS_H1 + 16448*512*2)     // bf16[8][64][256]
#define WS_W3T    (WS_W2T + 8*64*256*2)     // bf16[8][32][64]
#define WS_W4T    (WS_W3T + 8*32*64*2)      // bf16[8][16][32]  (n>=14 zero)
#define WS_R2T    (WS_W4T + 8*16*32*2)      // bf16[8][16][256] (n>=3 zero)

typedef __attribute__((ext_vector_type(8))) short bf16x8;
typedef __attribute__((ext_vector_type(4))) float f32x4;

__device__ __forceinline__ unsigned short f2bf(float f) {
    unsigned u = __float_as_uint(f);
    u += 0x7fffu + ((u >> 16) & 1u);   // RNE
    return (unsigned short)(u >> 16);
}

// fp32x8 -> bf16x8 convert + 16B LDS write (ds_write_b128)
__device__ __forceinline__ void cvt_wr16(short* dst, float4 a, float4 b) {
    unsigned u0 = (unsigned)f2bf(a.x) | ((unsigned)f2bf(a.y) << 16);
    unsigned u1 = (unsigned)f2bf(a.z) | ((unsigned)f2bf(a.w) << 16);
    unsigned u2 = (unsigned)f2bf(b.x) | ((unsigned)f2bf(b.y) << 16);
    unsigned u3 = (unsigned)f2bf(b.z) | ((unsigned)f2bf(b.w) << 16);
    *(uint4*)dst = make_uint4(u0, u1, u2, u3);
}

// async global->LDS, 16B per lane. LDS DEST = wave-uniform base + lane*16.
__device__ __forceinline__ void gl_lds16(const void* g, void* l) {
    __builtin_amdgcn_global_load_lds(
        (const __attribute__((address_space(1))) void*)g,
        (__attribute__((address_space(3))) void*)l,
        16, 0, 0);
}

// chunk id -> (expert, base, len) from the 9-entry prefix array. Uniform scalar loop.
__device__ __forceinline__ bool chunk_lookup(const int* __restrict__ offs, int c, int csize,
                                             int& e, int& base, int& len) {
    int acc = 0;
#pragma unroll
    for (int i = 0; i < NE; i++) {
        int s = offs[i], t = offs[i + 1];
        int cc = (t - s + csize - 1) / csize;
        if (c < acc + cc) {
            e = i;
            base = s + (c - acc) * csize;
            len = (t - base < csize) ? (t - base) : csize;
            return true;
        }
        acc += cc;
    }
    return false;
}

// ---------------- kernel 1: fused [wcvt | hist] ----------------
__global__ __launch_bounds__(256) void k_prep1(const float* __restrict__ W1,
                                               const float* __restrict__ R1,
                                               const float* __restrict__ W2,
                                               const float* __restrict__ W3,
                                               const float* __restrict__ W4,
                                               const float* __restrict__ R2,
                                               const int* __restrict__ sem,
                                               unsigned short* __restrict__ wt,
                                               unsigned short* __restrict__ w2t,
                                               unsigned short* __restrict__ w3t,
                                               unsigned short* __restrict__ w4t,
                                               unsigned short* __restrict__ r2t,
                                               int* __restrict__ ws_i) {
    __shared__ float tile[64][65];
    int id = blockIdx.x, tid = threadIdx.x;
    if (id >= 1024) {
        __shared__ int cnt[NE];
        int hb = id - 1024, lane = tid & 63;
        if (tid < NE) cnt[tid] = 0;
        __syncthreads();
        int s = sem[hb * 256 + tid];
#pragma unroll
        for (int e = 0; e < NE; e++) {
            unsigned long long m = __ballot(s == e);
            if (lane == e) atomicAdd(&cnt[e], (int)__popcll(m));
        }
        __syncthreads();
        if (tid < NE) ws_i[(WS_PART >> 2) + hb * NE + tid] = cnt[tid];
        return;
    }
    int e = id >> 7, rem = id & 127;
    int ny = rem >> 4, kx = rem & 15;
    int k0 = kx * 64, n0 = ny * 64;
    const float* src = (n0 < 256) ? (W1 + (size_t)e * 1024 * 256 + n0)
                                  : (R1 + (size_t)e * 1024 * 256 + (n0 - 256));
    int rr = tid >> 4;
    int cg = (tid & 15) * 4;
#pragma unroll
    for (int p = 0; p < 4; p++) {
        int kk = p * 16 + rr;
        float4 v = *(const float4*)(src + (size_t)(k0 + kk) * 256 + cg);
        tile[kk][cg] = v.x; tile[kk][cg + 1] = v.y; tile[kk][cg + 2] = v.z; tile[kk][cg + 3] = v.w;
    }
    __syncthreads();
    int nn = tid >> 3;
    int k8 = tid & 7;
#pragma unroll
    for (int p = 0; p < 2; p++) {
        int n = p * 32 + nn;
        unsigned w[4];
#pragma unroll
        for (int j = 0; j < 4; j++) {
            float f0 = tile[k8 * 8 + 2 * j][n];
            float f1 = tile[k8 * 8 + 2 * j + 1][n];
            w[j] = (unsigned)f2bf(f0) | ((unsigned)f2bf(f1) << 16);
        }
        *(uint4*)(wt + (size_t)(e * 512 + n0 + n) * 1024 + k0 + k8 * 8) =
            make_uint4(w[0], w[1], w[2], w[3]);
    }
    if (ny == 0) {
        int x = kx;
        for (int j = tid; j < 1024; j += 256) {
            int idx = x * 1024 + j; int k = idx & 255, n = idx >> 8;
            w2t[(size_t)(e * 64 + n) * 256 + k] = f2bf(W2[(size_t)e * 16384 + k * 64 + n]);
        }
        if (tid < 128) {
            int idx = x * 128 + tid; int k = idx & 63, n = idx >> 6;
            w3t[(size_t)(e * 32 + n) * 64 + k] = f2bf(W3[(size_t)e * 2048 + k * 32 + n]);
        }
        if (tid < 32) {
            int idx = x * 32 + tid; int k = idx & 31, n = idx >> 5;
            w4t[(size_t)(e * 16 + n) * 32 + k] = (n < 14) ? f2bf(W4[(size_t)e * 448 + k * 14 + n])
                                                          : (unsigned short)0;
        }
        {
            int idx = x * 256 + tid; int k = idx & 255, n = idx >> 8;
            r2t[(size_t)(e * 16 + n) * 256 + k] = (n < 3) ? f2bf(R2[(size_t)e * 768 + k * 3 + n])
                                                          : (unsigned short)0;
        }
    }
}

// ---------------- kernel 2: perm-only ----------------
__global__ __launch_bounds__(256) void k_perm(const int* __restrict__ sem,
                                              int* __restrict__ ws_i) {
    __shared__ int parts[512];
    __shared__ int tot[NE], preb[NE], ebase[NE + 1];
    __shared__ int wcnt[4][NE];
    int g = blockIdx.x;
    int tid = threadIdx.x, wave = tid >> 6, lane = tid & 63;
    parts[tid] = ws_i[(WS_PART >> 2) + tid];
    parts[256 + tid] = ws_i[(WS_PART >> 2) + 256 + tid];
    __syncthreads();
    if (tid < NE) {
        int t = 0, p = 0;
        for (int bb = 0; bb < 64; bb++) {
            int v = parts[bb * NE + tid];
            t += v;
            if (bb < g) p += v;
        }
        tot[tid] = t; preb[tid] = p;
    }
    __syncthreads();
    if (tid == 0) {
        int base = 0;
        for (int e = 0; e < NE; e++) { ebase[e] = base; base += tot[e]; }
        ebase[NE] = base;
        if (g == 0)
            for (int e = 0; e <= NE; e++) ws_i[(WS_OFFS >> 2) + e] = ebase[e];
    }
    int i = g * 256 + tid;
    int s = sem[i];
    int rank = 0;
#pragma unroll
    for (int e = 0; e < NE; e++) {
        unsigned long long m = __ballot(s == e);
        if (s == e) rank = (int)__popcll(m & ((1ull << lane) - 1ull));
        if (lane == e) wcnt[wave][e] = (int)__popcll(m);
    }
    __syncthreads();   // orders ebase (tid0) AND wcnt writes before reads below
    int wpre = 0;
#pragma unroll
    for (int w = 0; w < 4; w++)
        if (w < wave) wpre += wcnt[w][s];
    int dest = ebase[s] + preb[s] + wpre + rank;
    ws_i[(WS_PERM >> 2) + dest] = i;
}

// ---------------- kernel 3: layer-1 GEMM — gather-A with R12's counted-wait invariant ----------------
// R9 post-mortem: gather-A traffic WON (FETCH 66.7->43.4MB) but the schedule drained vmcnt
// to 0 each step -> pipeline restarted cold (77us). This version restores the R12 invariant:
// something is ALWAYS in flight across the barrier. Unroll-by-2, two named A-reg sets (E/O):
//   issue B(kb+1) DMA -> compute(kb) -> cvt A(kb+1) (regs issued LAST iter: latency hidden)
//   -> issue A(kb+2) regs -> vmcnt(4): B(kb+1) done, A(kb+2) stays in flight across barrier.
#define LOADA_E(kb) do { \
    e0a = *(const float4*)(apA[0] + (kb) * 64); e0b = *(const float4*)(apA[0] + (kb) * 64 + 4); \
    e1a = *(const float4*)(apA[1] + (kb) * 64); e1b = *(const float4*)(apA[1] + (kb) * 64 + 4); } while (0)
#define LOADA_O(kb) do { \
    o0a = *(const float4*)(apA[0] + (kb) * 64); o0b = *(const float4*)(apA[0] + (kb) * 64 + 4); \
    o1a = *(const float4*)(apA[1] + (kb) * 64); o1b = *(const float4*)(apA[1] + (kb) * 64 + 4); } while (0)
#define ISSUEB(kb, bufi) do { \
    _Pragma("unroll") \
    for (int i_ = 0; i_ < 4; i_++) gl_lds16(srcB[i_] + (kb) * 64, &Bs[bufi][dstB[i_]]); } while (0)
#define COMPUTE(bufi) do { \
    const short* Ab_ = As[bufi]; \
    const short* Bb_ = Bs[bufi]; \
    bf16x8 af_[2][4], bfr_[2][2]; \
    _Pragma("unroll") \
    for (int im_ = 0; im_ < 4; im_++) { \
        int r_ = im_ * 16 + lr; \
        _Pragma("unroll") \
        for (int kh_ = 0; kh_ < 2; kh_++) { \
            int q_ = kh_ * 4 + quad; \
            af_[kh_][im_] = *(const bf16x8*)(Ab_ + (r_ * 8 + (q_ ^ (r_ & 7))) * 8); \
        } \
    } \
    _Pragma("unroll") \
    for (int in_ = 0; in_ < 2; in_++) { \
        int r_ = wn + in_ * 16 + lr; \
        _Pragma("unroll") \
        for (int kh_ = 0; kh_ < 2; kh_++) { \
            int q_ = kh_ * 4 + quad; \
            bfr_[kh_][in_] = *(const bf16x8*)(Bb_ + (r_ * 8 + (q_ ^ (r_ & 7))) * 8); \
        } \
    } \
    _Pragma("unroll") \
    for (int kh_ = 0; kh_ < 2; kh_++) \
    _Pragma("unroll") \
    for (int im_ = 0; im_ < 4; im_++) \
    _Pragma("unroll") \
    for (int in_ = 0; in_ < 2; in_++) \
        acc[im_][in_] = __builtin_amdgcn_mfma_f32_16x16x32_bf16(af_[kh_][im_], bfr_[kh_][in_], acc[im_][in_], 0, 0, 0); \
    } while (0)

__global__ __launch_bounds__(256) void k_gemm(const float* __restrict__ nodes,
                                              const unsigned short* __restrict__ wt,
                                              const float* __restrict__ b1,
                                              const float* __restrict__ rb1,
                                              const int* __restrict__ ws_i,
                                              unsigned short* __restrict__ h1) {
    __shared__ __align__(16) short As[2][64 * 64];    // 16 KB
    __shared__ __align__(16) short Bs[2][128 * 64];   // 32 KB
    int bid = blockIdx.x;
    int wgid = (bid & 7) * ((MAXC64 * 4) / 8) + (bid >> 3);   // bijective: 1056 = 8*132
    int c = wgid >> 2, nblk = wgid & 3;
    int e, base, len;
    if (!chunk_lookup(ws_i + (WS_OFFS >> 2), c, 64, e, base, len)) return;
    int n0 = nblk * 128;
    int tid = threadIdx.x;
    int wave = tid >> 6, lane = tid & 63;
    int quad = lane >> 4, lr = lane & 15;
    int wn = wave * 32;   // each wave: all 64 rows x 32 cols

    f32x4 acc[4][2];
#pragma unroll
    for (int i = 0; i < 4; i++)
#pragma unroll
        for (int j = 0; j < 2; j++) acc[i][j] = (f32x4){0.f, 0.f, 0.f, 0.f};

    const int* perm = ws_i + (WS_PERM >> 2);
    const unsigned short* Bg = wt + (size_t)(e * 512 + n0) * 1024;

    // A gather geometry (verified R9): slot s=i*256+tid; row r=s>>3; swz chunk cs=(s&7)^(r&7);
    // per-lane global src = nodes[perm[base+r]] + cs*8 floats; LINEAR LDS dest at s*16B.
    const float* apA[2];
    int dstA[2];
#pragma unroll
    for (int i = 0; i < 2; i++) {
        int s = i * 256 + tid;
        int r = s >> 3, cs = (s & 7) ^ (r & 7);
        int gidx = base + r;
        if (gidx > T_TOK - 1) gidx = T_TOK - 1;   // last-chunk slack: clamp (masked at epilogue)
        int tok = perm[gidx];
        apA[i] = nodes + (size_t)tok * 1024 + cs * 8;
        dstA[i] = s * 8;
    }
    const unsigned short* srcB[4];
    int dstB[4];
#pragma unroll
    for (int i = 0; i < 4; i++) {
        int s = i * 256 + wave * 64 + lane;
        int r = s >> 3, cs = (s & 7) ^ (r & 7);
        srcB[i] = Bg + (size_t)r * 1024 + cs * 8;
        dstB[i] = (i * 256 + wave * 64) * 8;
    }

    float4 e0a, e0b, e1a, e1b;   // even A-reg set (steps 0,2,4,..)
    float4 o0a, o0b, o1a, o1b;   // odd  A-reg set (steps 1,3,5,..)

    // prologue: A(0) regs + B(0) DMA; cvt A(0); issue A(1); vmcnt(4)=B(0) done, A(1) in flight.
    LOADA_E(0);
    ISSUEB(0, 0);
    __builtin_amdgcn_sched_barrier(0);
    cvt_wr16(&As[0][dstA[0]], e0a, e0b);
    cvt_wr16(&As[0][dstA[1]], e1a, e1b);
    LOADA_O(1);
    asm volatile("s_waitcnt vmcnt(4) lgkmcnt(0)" ::: "memory");
    __builtin_amdgcn_sched_barrier(0);
    __builtin_amdgcn_s_barrier();

    for (int kb = 0; kb < 14; kb += 2) {
        // even step kb: cur=0, nxt=1; A(kb+1) regs (O set) in flight since last iteration
        ISSUEB(kb + 1, 1);
        __builtin_amdgcn_sched_barrier(0);   // pin B issue above compute
        COMPUTE(0);
        cvt_wr16(&As[1][dstA[0]], o0a, o0b);   // compiler waits A(kb+1) regs here
        cvt_wr16(&As[1][dstA[1]], o1a, o1b);
        LOADA_E(kb + 2);                        // A(kb+2): in flight across the barrier
        asm volatile("s_waitcnt vmcnt(4) lgkmcnt(0)" ::: "memory");   // B(kb+1) done
        __builtin_amdgcn_sched_barrier(0);
        __builtin_amdgcn_s_barrier();

        // odd step kb+1: cur=1, nxt=0
        ISSUEB(kb + 2, 0);
        __builtin_amdgcn_sched_barrier(0);
        COMPUTE(1);
        cvt_wr16(&As[0][dstA[0]], e0a, e0b);
        cvt_wr16(&As[0][dstA[1]], e1a, e1b);
        LOADA_O(kb + 3);
        asm volatile("s_waitcnt vmcnt(4) lgkmcnt(0)" ::: "memory");
        __builtin_amdgcn_sched_barrier(0);
        __builtin_amdgcn_s_barrier();
    }
    // step 14 (cur=0): A(15) regs (O set, issued at kb=12 odd body) in flight
    ISSUEB(15, 1);
    __builtin_amdgcn_sched_barrier(0);
    COMPUTE(0);
    cvt_wr16(&As[1][dstA[0]], o0a, o0b);
    cvt_wr16(&As[1][dstA[1]], o1a, o1b);
    asm volatile("s_waitcnt vmcnt(0) lgkmcnt(0)" ::: "memory");
    __builtin_amdgcn_sched_barrier(0);
    __builtin_amdgcn_s_barrier();
    // step 15 (cur=1)
    COMPUTE(1);

    // epilogue: + bias, relu, store bf16. C/D layout: col=lane&15, row=quad*4+reg.
#pragma unroll
    for (int in = 0; in < 2; in++) {
        int gcol = n0 + wn + in * 16 + lr;
        float bias = (gcol < 256) ? b1[e * 256 + gcol] : rb1[e * 256 + gcol - 256];
#pragma unroll
        for (int im = 0; im < 4; im++) {
#pragma unroll
            for (int v = 0; v < 4; v++) {
                int r = im * 16 + quad * 4 + v;
                if (r < len) {
                    float val = fmaxf(acc[im][in][v] + bias, 0.f);
                    h1[(size_t)(base + r) * 512 + gcol] = f2bf(val);
                }
            }
        }
    }
}

// ---------------- kernel 4: MFMA tail — 16-token blocks, 4x wave parallelism ----------------
__global__ __launch_bounds__(256) void k_tail(const unsigned short* __restrict__ h1,
                                              const int* __restrict__ ws_i,
                                              const unsigned short* __restrict__ w2t,
                                              const unsigned short* __restrict__ w3t,
                                              const unsigned short* __restrict__ w4t,
                                              const unsigned short* __restrict__ r2t,
                                              const float* __restrict__ b2,
                                              const float* __restrict__ b3,
                                              const float* __restrict__ b4,
                                              const float* __restrict__ rb2,
                                              const int* __restrict__ lengths,
                                              float* __restrict__ out) {
    __shared__ __align__(16) unsigned short h2s[16][64];
    __shared__ __align__(16) unsigned short h3s[16][32];

    int e, base, len;
    if (!chunk_lookup(ws_i + (WS_OFFS >> 2), blockIdx.x, 16, e, base, len)) return;
    int tid = threadIdx.x, wave = tid >> 6, lane = tid & 63;
    int quad = lane >> 4, lr = lane & 15;
    int lead = blockIdx.x & 3;   // rotate leader role across blocks

    const unsigned short* Ap = h1 + (size_t)base * 512;

    // layer 2: wave w computes output cols w*16..w*16+15 for all 16 tokens
    f32x4 acc2;
    { float bb = b2[e * 64 + wave * 16 + lr]; acc2 = (f32x4){bb, bb, bb, bb}; }
    f32x4 accr;
    { float bb = (lr < 3) ? rb2[e * 3 + lr] : 0.f; accr = (f32x4){bb, bb, bb, bb}; }

    const unsigned short* W2e = w2t + (size_t)e * 64 * 256;
    const unsigned short* R2e = r2t + (size_t)e * 16 * 256;
#pragma unroll
    for (int kk = 0; kk < 8; kk++) {
        int k0 = kk * 32;
        bf16x8 a = *(const bf16x8*)(Ap + lr * 512 + k0 + quad * 8);
        bf16x8 b = *(const bf16x8*)(W2e + (wave * 16 + lr) * 256 + k0 + quad * 8);
        acc2 = __builtin_amdgcn_mfma_f32_16x16x32_bf16(a, b, acc2, 0, 0, 0);
        if (wave == lead) {   // leader also accumulates the rot path (cols 256..511 of h1)
            bf16x8 ar = *(const bf16x8*)(Ap + lr * 512 + 256 + k0 + quad * 8);
            bf16x8 br = *(const bf16x8*)(R2e + lr * 256 + k0 + quad * 8);
            accr = __builtin_amdgcn_mfma_f32_16x16x32_bf16(ar, br, accr, 0, 0, 0);
        }
    }
#pragma unroll
    for (int v = 0; v < 4; v++)
        h2s[quad * 4 + v][wave * 16 + lr] = f2bf(fmaxf(acc2[v], 0.f));
    __syncthreads();
    if (wave != lead) return;

    // layer 3 (leader wave): K=64, N=32
    f32x4 acc3[2];
#pragma unroll
    for (int t = 0; t < 2; t++) {
        float bb = b3[e * 32 + t * 16 + lr];
        acc3[t] = (f32x4){bb, bb, bb, bb};
    }
    const unsigned short* W3e = w3t + (size_t)e * 32 * 64;
#pragma unroll
    for (int kk = 0; kk < 2; kk++) {
        int k0 = kk * 32;
        bf16x8 a = *(const bf16x8*)(&h2s[lr][k0 + quad * 8]);
#pragma unroll
        for (int t = 0; t < 2; t++) {
            bf16x8 b = *(const bf16x8*)(W3e + (t * 16 + lr) * 64 + k0 + quad * 8);
            acc3[t] = __builtin_amdgcn_mfma_f32_16x16x32_bf16(a, b, acc3[t], 0, 0, 0);
        }
    }
#pragma unroll
    for (int t = 0; t < 2; t++)
#pragma unroll
        for (int v = 0; v < 4; v++)
            h3s[quad * 4 + v][t * 16 + lr] = f2bf(fmaxf(acc3[t][v], 0.f));

    // layer 4: K=32, N=14 (padded 16)
    f32x4 acc4;
    { float bb = (lr < 14) ? b4[e * 14 + lr] : 0.f; acc4 = (f32x4){bb, bb, bb, bb}; }
    {
        bf16x8 a = *(const bf16x8*)(&h3s[lr][quad * 8]);
        bf16x8 b = *(const bf16x8*)(w4t + ((size_t)e * 16 + lr) * 32 + quad * 8);
        acc4 = __builtin_amdgcn_mfma_f32_16x16x32_bf16(a, b, acc4, 0, 0, 0);
    }

    const int* perm = ws_i + (WS_PERM >> 2);
#pragma unroll
    for (int v = 0; v < 4; v++) {
        int t = quad * 4 + v;
        if (t < len) {
            int token = perm[base + t];
            int bi = token >> 9, ni = token & 511;
            int valid = ni < lengths[bi];
            if (lr < 14) out[(size_t)token * 17 + lr] = valid ? acc4[v] : EPSV;
            if (lr < 3)  out[(size_t)token * 17 + 14 + lr] = valid ? accr[v] : EPSV;
        }
    }
}

extern "C" void kernel_launch(void* const* d_in, const int* in_sizes, int n_in,
                              void* d_out, int out_size, void* d_ws, size_t ws_size,
                              hipStream_t stream) {
    (void)in_sizes; (void)n_in; (void)out_size; (void)ws_size;
    const float* nodes   = (const float*)d_in[0];
    const int*   sem     = (const int*)d_in[1];
    const int*   lengths = (const int*)d_in[2];
    const float* W1 = (const float*)d_in[3];
    const float* b1 = (const float*)d_in[4];
    const float* W2 = (const float*)d_in[5];
    const float* b2 = (const float*)d_in[6];
    const float* W3 = (const float*)d_in[7];
    const float* b3 = (const float*)d_in[8];
    const float* W4 = (const float*)d_in[9];
    const float* b4 = (const float*)d_in[10];
    const float* R1  = (const float*)d_in[11];
    const float* rb1 = (const float*)d_in[12];
    const float* R2  = (const float*)d_in[13];
    const float* rb2 = (const float*)d_in[14];
    float* out = (float*)d_out;

    char* ws = (char*)d_ws;
    int* ws_i = (int*)ws;
    unsigned short* wt  = (unsigned short*)(ws + WS_WT);
    unsigned short* h1  = (unsigned short*)(ws + WS_H1);
    unsigned short* w2t = (unsigned short*)(ws + WS_W2T);
    unsigned short* w3t = (unsigned short*)(ws + WS_W3T);
    unsigned short* w4t = (unsigned short*)(ws + WS_W4T);
    unsigned short* r2t = (unsigned short*)(ws + WS_R2T);

    hipLaunchKernelGGL(k_prep1, dim3(1088), dim3(256), 0, stream,
                       W1, R1, W2, W3, W4, R2, sem, wt, w2t, w3t, w4t, r2t, ws_i);
    hipLaunchKernelGGL(k_perm, dim3(64), dim3(256), 0, stream, sem, ws_i);
    hipLaunchKernelGGL(k_gemm, dim3(MAXC64 * 4), dim3(256), 0, stream,
                       nodes, (const unsigned short*)wt, b1, rb1, (const int*)ws_i, h1);
    hipLaunchKernelGGL(k_tail, dim3(MAXC16), dim3(256), 0, stream,
                       (const unsigned short*)h1, (const int*)ws_i,
                       (const unsigned short*)w2t, (const unsigned short*)w3t,
                       (const unsigned short*)w4t, (const unsigned short*)r2t,
                       b2, b3, b4, rb2, lengths, out);
}

// Round 11
// 191.701 us; speedup vs baseline: 1.0721x; 1.0370x over previous
//
#include <hip/hip_runtime.h>
#include <stdint.h>

// Problem constants
#define T_TOK 16384     // 32*512 tokens
#define NE 8            // experts
#define EPSV 1e-8f
#define MAXC64  264     // max 64-token chunks
#define MAXC16  1032    // max 16-token chunks

// ws layout (byte offsets). Total ~56.8 MiB.
#define WS_PERM   0                         // int[16384]
#define WS_PART   65536                     // int[64][8] per-block expert counts
#define WS_OFFS   67584                     // int[9]
#define WS_XS     131072                    // bf16[16512][1024] sorted (128 slack rows)
#define WS_WT     (WS_XS + 16512*1024*2)    // bf16[8][512][1024]  (W1|R1 transposed, B^T layout)
#define WS_H1     (WS_WT + 8*512*1024*2)    // bf16[16448][512] (64 slack rows)
#define WS_W2T    (WS_H1 + 16448*512*2)     // bf16[8][64][256]
#define WS_W3T    (WS_W2T + 8*64*256*2)     // bf16[8][32][64]
#define WS_W4T    (WS_W3T + 8*32*64*2)      // bf16[8][16][32]  (n>=14 zero)
#define WS_R2T    (WS_W4T + 8*16*32*2)      // bf16[8][16][256] (n>=3 zero)

typedef __attribute__((ext_vector_type(8))) short bf16x8;
typedef __attribute__((ext_vector_type(4))) float f32x4;

__device__ __forceinline__ unsigned short f2bf(float f) {
    unsigned u = __float_as_uint(f);
    u += 0x7fffu + ((u >> 16) & 1u);   // RNE
    return (unsigned short)(u >> 16);
}

// async global->LDS, 16B per lane. LDS DEST = wave-uniform base + lane*16.
__device__ __forceinline__ void gl_lds16(const void* g, void* l) {
    __builtin_amdgcn_global_load_lds(
        (const __attribute__((address_space(1))) void*)g,
        (__attribute__((address_space(3))) void*)l,
        16, 0, 0);
}

// chunk id -> (expert, base, len) from the 9-entry prefix array. Uniform scalar loop.
__device__ __forceinline__ bool chunk_lookup(const int* __restrict__ offs, int c, int csize,
                                             int& e, int& base, int& len) {
    int acc = 0;
#pragma unroll
    for (int i = 0; i < NE; i++) {
        int s = offs[i], t = offs[i + 1];
        int cc = (t - s + csize - 1) / csize;
        if (c < acc + cc) {
            e = i;
            base = s + (c - acc) * csize;
            len = (t - base < csize) ? (t - base) : csize;
            return true;
        }
        acc += cc;
    }
    return false;
}

// ---------------- kernel 1: fused [wcvt | hist] ----------------
// blocks 0..1023:    W1|R1 transpose-convert (+ tail-weight convert on ny==0)
// blocks 1024..1087: per-block expert histogram of sem
__global__ __launch_bounds__(256) void k_prep1(const float* __restrict__ W1,
                                               const float* __restrict__ R1,
                                               const float* __restrict__ W2,
                                               const float* __restrict__ W3,
                                               const float* __restrict__ W4,
                                               const float* __restrict__ R2,
                                               const int* __restrict__ sem,
                                               unsigned short* __restrict__ wt,
                                               unsigned short* __restrict__ w2t,
                                               unsigned short* __restrict__ w3t,
                                               unsigned short* __restrict__ w4t,
                                               unsigned short* __restrict__ r2t,
                                               int* __restrict__ ws_i) {
    __shared__ float tile[64][65];
    int id = blockIdx.x, tid = threadIdx.x;
    if (id >= 1024) {
        __shared__ int cnt[NE];
        int hb = id - 1024, lane = tid & 63;
        if (tid < NE) cnt[tid] = 0;
        __syncthreads();
        int s = sem[hb * 256 + tid];
#pragma unroll
        for (int e = 0; e < NE; e++) {
            unsigned long long m = __ballot(s == e);
            if (lane == e) atomicAdd(&cnt[e], (int)__popcll(m));
        }
        __syncthreads();
        if (tid < NE) ws_i[(WS_PART >> 2) + hb * NE + tid] = cnt[tid];
        return;
    }
    int e = id >> 7, rem = id & 127;
    int ny = rem >> 4, kx = rem & 15;
    int k0 = kx * 64, n0 = ny * 64;
    const float* src = (n0 < 256) ? (W1 + (size_t)e * 1024 * 256 + n0)
                                  : (R1 + (size_t)e * 1024 * 256 + (n0 - 256));
    int rr = tid >> 4;
    int cg = (tid & 15) * 4;
#pragma unroll
    for (int p = 0; p < 4; p++) {
        int kk = p * 16 + rr;
        float4 v = *(const float4*)(src + (size_t)(k0 + kk) * 256 + cg);
        tile[kk][cg] = v.x; tile[kk][cg + 1] = v.y; tile[kk][cg + 2] = v.z; tile[kk][cg + 3] = v.w;
    }
    __syncthreads();
    int nn = tid >> 3;
    int k8 = tid & 7;
#pragma unroll
    for (int p = 0; p < 2; p++) {
        int n = p * 32 + nn;
        unsigned w[4];
#pragma unroll
        for (int j = 0; j < 4; j++) {
            float f0 = tile[k8 * 8 + 2 * j][n];
            float f1 = tile[k8 * 8 + 2 * j + 1][n];
            w[j] = (unsigned)f2bf(f0) | ((unsigned)f2bf(f1) << 16);
        }
        *(uint4*)(wt + (size_t)(e * 512 + n0 + n) * 1024 + k0 + k8 * 8) =
            make_uint4(w[0], w[1], w[2], w[3]);
    }
    if (ny == 0) {
        int x = kx;
        for (int j = tid; j < 1024; j += 256) {
            int idx = x * 1024 + j; int k = idx & 255, n = idx >> 8;
            w2t[(size_t)(e * 64 + n) * 256 + k] = f2bf(W2[(size_t)e * 16384 + k * 64 + n]);
        }
        if (tid < 128) {
            int idx = x * 128 + tid; int k = idx & 63, n = idx >> 6;
            w3t[(size_t)(e * 32 + n) * 64 + k] = f2bf(W3[(size_t)e * 2048 + k * 32 + n]);
        }
        if (tid < 32) {
            int idx = x * 32 + tid; int k = idx & 31, n = idx >> 5;
            w4t[(size_t)(e * 16 + n) * 32 + k] = (n < 14) ? f2bf(W4[(size_t)e * 448 + k * 14 + n])
                                                          : (unsigned short)0;
        }
        {
            int idx = x * 256 + tid; int k = idx & 255, n = idx >> 8;
            r2t[(size_t)(e * 16 + n) * 256 + k] = (n < 3) ? f2bf(R2[(size_t)e * 768 + k * 3 + n])
                                                          : (unsigned short)0;
        }
    }
}

// ---------------- kernel 2: scatter + sorted gather-convert ----------------
// 512 blocks = 8 siblings per 256-token group g. Each sibling DETERMINISTICALLY
// recomputes dest[] for group g (ballot + per-wave prefix, NO atomics), then copies its
// 32-row slice of nodes fp32 -> sorted bf16 xs (coalesced). Sibling j==0 writes perm/offs.
__global__ __launch_bounds__(256) void k_scatter(const int* __restrict__ sem,
                                                 const float* __restrict__ nodes,
                                                 int* __restrict__ ws_i,
                                                 unsigned short* __restrict__ xs) {
    __shared__ int parts[512];
    __shared__ int tot[NE], preb[NE], ebase[NE + 1];
    __shared__ int wcnt[4][NE];
    __shared__ int destS[256];
    int b = blockIdx.x, g = b >> 3, j = b & 7;
    int tid = threadIdx.x, wave = tid >> 6, lane = tid & 63;
    parts[tid] = ws_i[(WS_PART >> 2) + tid];
    parts[256 + tid] = ws_i[(WS_PART >> 2) + 256 + tid];
    __syncthreads();
    if (tid < NE) {
        int t = 0, p = 0;
        for (int bb = 0; bb < 64; bb++) {
            int v = parts[bb * NE + tid];
            t += v;
            if (bb < g) p += v;
        }
        tot[tid] = t; preb[tid] = p;
    }
    __syncthreads();
    if (tid == 0) {
        int base = 0;
        for (int e = 0; e < NE; e++) { ebase[e] = base; base += tot[e]; }
        ebase[NE] = base;
        if (b == 0)
            for (int e = 0; e <= NE; e++) ws_i[(WS_OFFS >> 2) + e] = ebase[e];
    }
    int i = g * 256 + tid;
    int s = sem[i];
    int rank = 0;
#pragma unroll
    for (int e = 0; e < NE; e++) {
        unsigned long long m = __ballot(s == e);
        if (s == e) rank = (int)__popcll(m & ((1ull << lane) - 1ull));
        if (lane == e) wcnt[wave][e] = (int)__popcll(m);
    }
    __syncthreads();
    int wpre = 0;
#pragma unroll
    for (int w = 0; w < 4; w++)
        if (w < wave) wpre += wcnt[w][s];
    int dest = ebase[s] + preb[s] + wpre + rank;
    destS[tid] = dest;
    if (j == 0) ws_i[(WS_PERM >> 2) + dest] = i;
    __syncthreads();
    // copy slice: rows r = j*32 .. j*32+31; each thread converts 4 floats/row
#pragma unroll 4
    for (int r = j * 32; r < j * 32 + 32; r++) {
        int tok = g * 256 + r;
        int d = destS[r];
        float4 v = *(const float4*)(nodes + (size_t)tok * 1024 + tid * 4);
        unsigned p0 = (unsigned)f2bf(v.x) | ((unsigned)f2bf(v.y) << 16);
        unsigned p1 = (unsigned)f2bf(v.z) | ((unsigned)f2bf(v.w) << 16);
        *(uint2*)(xs + (size_t)d * 1024 + tid * 4) = make_uint2(p0, p1);
    }
}

// ---------------- kernel 3: layer-1 GEMM — R12-verified depth-2 counted-vmcnt ----------------
// Session-best configuration (42-43us). Depth-2 @48KB LDS is the schedule optimum:
// depth-1 (48.8), syncthreads-dbuf (60), depth-3 (54.5), no-LDS (120), gather-A (64.5)
// all verified worse. Counted vmcnt(6): next step's 6 DMA stay in flight across barrier.
__global__ __launch_bounds__(256) void k_gemm(const unsigned short* __restrict__ xs,
                                              const unsigned short* __restrict__ wt,
                                              const float* __restrict__ b1,
                                              const float* __restrict__ rb1,
                                              const int* __restrict__ ws_i,
                                              unsigned short* __restrict__ h1) {
    __shared__ __align__(16) short As[2][64 * 64];    // 16 KB
    __shared__ __align__(16) short Bs[2][128 * 64];   // 32 KB
    int e, base, len;
    if (!chunk_lookup(ws_i + (WS_OFFS >> 2), blockIdx.x, 64, e, base, len)) return;
    int n0 = blockIdx.y * 128;
    int tid = threadIdx.x;
    int wave = tid >> 6, lane = tid & 63;
    int quad = lane >> 4, lr = lane & 15;
    int wn = wave * 32;   // each wave: all 64 rows x 32 cols

    f32x4 acc[4][2];
#pragma unroll
    for (int i = 0; i < 4; i++)
#pragma unroll
        for (int j = 0; j < 2; j++) acc[i][j] = (f32x4){0.f, 0.f, 0.f, 0.f};

    const unsigned short* Ag = xs + (size_t)base * 1024;
    const unsigned short* Bg = wt + (size_t)(e * 512 + n0) * 1024;

    const unsigned short* srcA[2];
    int dstA[2];
#pragma unroll
    for (int i = 0; i < 2; i++) {
        int s = i * 256 + wave * 64 + lane;
        int r = s >> 3, cs = (s & 7) ^ (r & 7);
        srcA[i] = Ag + (size_t)r * 1024 + cs * 8;
        dstA[i] = (i * 256 + wave * 64) * 8;
    }
    const unsigned short* srcB[4];
    int dstB[4];
#pragma unroll
    for (int i = 0; i < 4; i++) {
        int s = i * 256 + wave * 64 + lane;
        int r = s >> 3, cs = (s & 7) ^ (r & 7);
        srcB[i] = Bg + (size_t)r * 1024 + cs * 8;
        dstB[i] = (i * 256 + wave * 64) * 8;
    }

    // prologue: stage step 0 into buffer 0 (6 VMEM ops per wave)
#pragma unroll
    for (int i = 0; i < 2; i++) gl_lds16(srcA[i], &As[0][dstA[i]]);
#pragma unroll
    for (int i = 0; i < 4; i++) gl_lds16(srcB[i], &Bs[0][dstB[i]]);

    for (int kb = 0; kb < 16; kb++) {
        int cur = kb & 1;
        if (kb < 15) {
            int nxt = cur ^ 1;
#pragma unroll
            for (int i = 0; i < 2; i++) gl_lds16(srcA[i] + (kb + 1) * 64, &As[nxt][dstA[i]]);
#pragma unroll
            for (int i = 0; i < 4; i++) gl_lds16(srcB[i] + (kb + 1) * 64, &Bs[nxt][dstB[i]]);
            asm volatile("s_waitcnt vmcnt(6)" ::: "memory");
        } else {
            asm volatile("s_waitcnt vmcnt(0)" ::: "memory");
        }
        __builtin_amdgcn_sched_barrier(0);
        __builtin_amdgcn_s_barrier();

        const short* Ab = As[cur];
        const short* Bb = Bs[cur];
        bf16x8 af[2][4], bfr[2][2];
#pragma unroll
        for (int im = 0; im < 4; im++) {
            int r = im * 16 + lr;
#pragma unroll
            for (int kh = 0; kh < 2; kh++) {
                int q = kh * 4 + quad;
                af[kh][im] = *(const bf16x8*)(Ab + (r * 8 + (q ^ (r & 7))) * 8);
            }
        }
#pragma unroll
        for (int in = 0; in < 2; in++) {
            int r = wn + in * 16 + lr;
#pragma unroll
            for (int kh = 0; kh < 2; kh++) {
                int q = kh * 4 + quad;
                bfr[kh][in] = *(const bf16x8*)(Bb + (r * 8 + (q ^ (r & 7))) * 8);
            }
        }
#pragma unroll
        for (int kh = 0; kh < 2; kh++)
#pragma unroll
            for (int im = 0; im < 4; im++)
#pragma unroll
                for (int in = 0; in < 2; in++)
                    acc[im][in] = __builtin_amdgcn_mfma_f32_16x16x32_bf16(af[kh][im], bfr[kh][in], acc[im][in], 0, 0, 0);

        if (kb < 15) {
            __builtin_amdgcn_sched_barrier(0);
            __builtin_amdgcn_s_barrier();
        }
    }

    // epilogue: + bias, relu, store bf16. C/D layout: col=lane&15, row=quad*4+reg.
#pragma unroll
    for (int in = 0; in < 2; in++) {
        int gcol = n0 + wn + in * 16 + lr;
        float bias = (gcol < 256) ? b1[e * 256 + gcol] : rb1[e * 256 + gcol - 256];
#pragma unroll
        for (int im = 0; im < 4; im++) {
#pragma unroll
            for (int v = 0; v < 4; v++) {
                int r = im * 16 + quad * 4 + v;
                if (r < len) {
                    float val = fmaxf(acc[im][in][v] + bias, 0.f);
                    h1[(size_t)(base + r) * 512 + gcol] = f2bf(val);
                }
            }
        }
    }
}

// ---------------- kernel 4: MFMA tail — 16-token blocks, 4x wave parallelism ----------------
__global__ __launch_bounds__(256) void k_tail(const unsigned short* __restrict__ h1,
                                              const int* __restrict__ ws_i,
                                              const unsigned short* __restrict__ w2t,
                                              const unsigned short* __restrict__ w3t,
                                              const unsigned short* __restrict__ w4t,
                                              const unsigned short* __restrict__ r2t,
                                              const float* __restrict__ b2,
                                              const float* __restrict__ b3,
                                              const float* __restrict__ b4,
                                              const float* __restrict__ rb2,
                                              const int* __restrict__ lengths,
                                              float* __restrict__ out) {
    __shared__ __align__(16) unsigned short h2s[16][64];
    __shared__ __align__(16) unsigned short h3s[16][32];

    int e, base, len;
    if (!chunk_lookup(ws_i + (WS_OFFS >> 2), blockIdx.x, 16, e, base, len)) return;
    int tid = threadIdx.x, wave = tid >> 6, lane = tid & 63;
    int quad = lane >> 4, lr = lane & 15;
    int lead = blockIdx.x & 3;   // rotate leader role across blocks

    const unsigned short* Ap = h1 + (size_t)base * 512;

    // layer 2: wave w computes output cols w*16..w*16+15 for all 16 tokens
    f32x4 acc2;
    { float bb = b2[e * 64 + wave * 16 + lr]; acc2 = (f32x4){bb, bb, bb, bb}; }
    f32x4 accr;
    { float bb = (lr < 3) ? rb2[e * 3 + lr] : 0.f; accr = (f32x4){bb, bb, bb, bb}; }

    const unsigned short* W2e = w2t + (size_t)e * 64 * 256;
    const unsigned short* R2e = r2t + (size_t)e * 16 * 256;
#pragma unroll
    for (int kk = 0; kk < 8; kk++) {
        int k0 = kk * 32;
        bf16x8 a = *(const bf16x8*)(Ap + lr * 512 + k0 + quad * 8);
        bf16x8 b = *(const bf16x8*)(W2e + (wave * 16 + lr) * 256 + k0 + quad * 8);
        acc2 = __builtin_amdgcn_mfma_f32_16x16x32_bf16(a, b, acc2, 0, 0, 0);
        if (wave == lead) {   // leader also accumulates the rot path (cols 256..511 of h1)
            bf16x8 ar = *(const bf16x8*)(Ap + lr * 512 + 256 + k0 + quad * 8);
            bf16x8 br = *(const bf16x8*)(R2e + lr * 256 + k0 + quad * 8);
            accr = __builtin_amdgcn_mfma_f32_16x16x32_bf16(ar, br, accr, 0, 0, 0);
        }
    }
#pragma unroll
    for (int v = 0; v < 4; v++)
        h2s[quad * 4 + v][wave * 16 + lr] = f2bf(fmaxf(acc2[v], 0.f));
    __syncthreads();
    if (wave != lead) return;

    // layer 3 (leader wave): K=64, N=32
    f32x4 acc3[2];
#pragma unroll
    for (int t = 0; t < 2; t++) {
        float bb = b3[e * 32 + t * 16 + lr];
        acc3[t] = (f32x4){bb, bb, bb, bb};
    }
    const unsigned short* W3e = w3t + (size_t)e * 32 * 64;
#pragma unroll
    for (int kk = 0; kk < 2; kk++) {
        int k0 = kk * 32;
        bf16x8 a = *(const bf16x8*)(&h2s[lr][k0 + quad * 8]);
#pragma unroll
        for (int t = 0; t < 2; t++) {
            bf16x8 b = *(const bf16x8*)(W3e + (t * 16 + lr) * 64 + k0 + quad * 8);
            acc3[t] = __builtin_amdgcn_mfma_f32_16x16x32_bf16(a, b, acc3[t], 0, 0, 0);
        }
    }
#pragma unroll
    for (int t = 0; t < 2; t++)
#pragma unroll
        for (int v = 0; v < 4; v++)
            h3s[quad * 4 + v][t * 16 + lr] = f2bf(fmaxf(acc3[t][v], 0.f));

    // layer 4: K=32, N=14 (padded 16)
    f32x4 acc4;
    { float bb = (lr < 14) ? b4[e * 14 + lr] : 0.f; acc4 = (f32x4){bb, bb, bb, bb}; }
    {
        bf16x8 a = *(const bf16x8*)(&h3s[lr][quad * 8]);
        bf16x8 b = *(const bf16x8*)(w4t + ((size_t)e * 16 + lr) * 32 + quad * 8);
        acc4 = __builtin_amdgcn_mfma_f32_16x16x32_bf16(a, b, acc4, 0, 0, 0);
    }

    const int* perm = ws_i + (WS_PERM >> 2);
#pragma unroll
    for (int v = 0; v < 4; v++) {
        int t = quad * 4 + v;
        if (t < len) {
            int token = perm[base + t];
            int bi = token >> 9, ni = token & 511;
            int valid = ni < lengths[bi];
            if (lr < 14) out[(size_t)token * 17 + lr] = valid ? acc4[v] : EPSV;
            if (lr < 3)  out[(size_t)token * 17 + 14 + lr] = valid ? accr[v] : EPSV;
        }
    }
}

extern "C" void kernel_launch(void* const* d_in, const int* in_sizes, int n_in,
                              void* d_out, int out_size, void* d_ws, size_t ws_size,
                              hipStream_t stream) {
    (void)in_sizes; (void)n_in; (void)out_size; (void)ws_size;
    const float* nodes   = (const float*)d_in[0];
    const int*   sem     = (const int*)d_in[1];
    const int*   lengths = (const int*)d_in[2];
    const float* W1 = (const float*)d_in[3];
    const float* b1 = (const float*)d_in[4];
    const float* W2 = (const float*)d_in[5];
    const float* b2 = (const float*)d_in[6];
    const float* W3 = (const float*)d_in[7];
    const float* b3 = (const float*)d_in[8];
    const float* W4 = (const float*)d_in[9];
    const float* b4 = (const float*)d_in[10];
    const float* R1  = (const float*)d_in[11];
    const float* rb1 = (const float*)d_in[12];
    const float* R2  = (const float*)d_in[13];
    const float* rb2 = (const float*)d_in[14];
    float* out = (float*)d_out;

    char* ws = (char*)d_ws;
    int* ws_i = (int*)ws;
    unsigned short* xs  = (unsigned short*)(ws + WS_XS);
    unsigned short* wt  = (unsigned short*)(ws + WS_WT);
    unsigned short* h1  = (unsigned short*)(ws + WS_H1);
    unsigned short* w2t = (unsigned short*)(ws + WS_W2T);
    unsigned short* w3t = (unsigned short*)(ws + WS_W3T);
    unsigned short* w4t = (unsigned short*)(ws + WS_W4T);
    unsigned short* r2t = (unsigned short*)(ws + WS_R2T);

    hipLaunchKernelGGL(k_prep1, dim3(1088), dim3(256), 0, stream,
                       W1, R1, W2, W3, W4, R2, sem, wt, w2t, w3t, w4t, r2t, ws_i);
    hipLaunchKernelGGL(k_scatter, dim3(512), dim3(256), 0, stream, sem, nodes, ws_i, xs);
    hipLaunchKernelGGL(k_gemm, dim3(MAXC64, 4), dim3(256), 0, stream,
                       (const unsigned short*)xs, (const unsigned short*)wt, b1, rb1,
                       (const int*)ws_i, h1);
    hipLaunchKernelGGL(k_tail, dim3(MAXC16), dim3(256), 0, stream,
                       (const unsigned short*)h1, (const int*)ws_i,
                       (const unsigned short*)w2t, (const unsigned short*)w3t,
                       (const unsigned short*)w4t, (const unsigned short*)r2t,
                       b2, b3, b4, rb2, lengths, out);
}